// Round 7
// baseline (1317.835 us; speedup 1.0000x reference)
//
#include <hip/hip_runtime.h>

// VQ argmin: exact bit-level emulation of numpy fp32 reference:
//   A  = np.sum(flat*flat, axis=1)     (numpy pairwise-sum tree, fp32)
//   M2 = (2*flat) @ emb.T              (BLAS: sequential fp32 fma chain over d)
//   dist = (A - M2) + ee;  argmin_k (first-min ties)
// z_e_x: [B=16, D=256, H=64, W=64] fp32; embedding: [K=1024, D=256] fp32
// out: int32 [65536]
//
// R10: R9's LDS GEMM with the two measured defects fixed.
// (1) Bank conflicts (R9: 5.2e7 cycles, 4-way on z staging/reads at cols
//     nx*8): split-half micro-tile -- thread owns n in {lx*4..+3} u
//     {64+lx*4..+3}, k in {ky*4..+3} u {64+ky*4..+3}. Every 8-lane group
//     of every b128 LDS access covers banks 0-31 exactly once -> 0
//     conflicts (z reads, e reads broadcast, staging writes all checked).
// (2) Single-buffer + 2 barriers/chunk: now double-buffered (2x16KB),
//     1 barrier/chunk; staging writes overlap compute of the other buffer;
//     chunk c+2 global loads issued a full compute-chunk (~2048 cyc) ahead.
// Exactness unchanged: acc[n][k] = fmaf chain over d = (c,dd) ascending;
// dist = (An - acc) + ee; within-thread k ascending; cross-thread/block via
// u64 (distbits,k) atomicMin (verified R4/R5/R8/R9). Stack kept from R8:
// split a_kernel, tiled et, ee, memset+unpack.

#define D_DIM  256
#define K_DIM  1024
#define HW     4096
#define N_TOT  65536
#define BN     128                // n-tile per block
#define BK     128                // k-tile per block
#define NCH    16                 // d-chunks of 16
#define F32MAX 3.402823466e38f

// ---- numpy pairwise_sum for ||e_k||^2 (n=256 = two 128-blocks of 8 accs)

__global__ void ee_kernel(const float* __restrict__ e, float* __restrict__ ee) {
#pragma clang fp contract(off)
    int k = blockIdx.x * blockDim.x + threadIdx.x;
    if (k >= K_DIM) return;
    const float* row = e + (size_t)k * D_DIM;
    float total = 0.0f;
    #pragma unroll
    for (int h = 0; h < 2; ++h) {
        const float* a = row + h * 128;
        float r[8];
        #pragma unroll
        for (int j = 0; j < 8; ++j) { float v = a[j]; r[j] = v * v; }
        #pragma unroll
        for (int i = 8; i < 128; i += 8) {
            #pragma unroll
            for (int j = 0; j < 8; ++j) { float v = a[i + j]; r[j] = r[j] + v * v; }
        }
        float s = ((r[0] + r[1]) + (r[2] + r[3])) + ((r[4] + r[5]) + (r[6] + r[7]));
        total = (h == 0) ? s : (total + s);
    }
    ee[k] = total;
}

// ---- A = numpy pairwise ||z_n||^2: 2 threads per n, one 128-half each
// (halves are independent 8-acc chains; total = s0 + s1). Bitwise-exact.

__global__ void a_kernel(const float* __restrict__ z, float* __restrict__ A) {
#pragma clang fp contract(off)
    int t = blockIdx.x * blockDim.x + threadIdx.x;   // 0 .. 2*N_TOT-1
    int n = t >> 1;
    int h = t & 1;
    int b  = n >> 12;
    int hw = n & (HW - 1);
    const float* base = z + (size_t)b * D_DIM * HW + hw + (size_t)(h * 128) * HW;
    float r[8];
    #pragma unroll
    for (int j = 0; j < 8; ++j) { float v = base[(size_t)j * HW]; r[j] = v * v; }
    #pragma unroll
    for (int i = 8; i < 128; i += 8) {
        #pragma unroll
        for (int j = 0; j < 8; ++j) {
            float v = base[(size_t)(i + j) * HW];
            r[j] = r[j] + v * v;
        }
    }
    float s = ((r[0] + r[1]) + (r[2] + r[3])) + ((r[4] + r[5]) + (r[6] + r[7]));
    float other = __shfl_xor(s, 1);
    if (h == 0) A[n] = s + other;    // total = s_half0 + s_half1 (exact order)
}

// ---- transpose + fold the exact x2: eT[d][k] = 2*emb[k][d]

__global__ void et_kernel(const float* __restrict__ e, float* __restrict__ eT) {
    __shared__ float t[32][33];
    const int k0 = blockIdx.x * 32;
    const int d0 = blockIdx.y * 32;
    const int tx = threadIdx.x;         // 0..31
    const int ty = threadIdx.y;         // 0..7
    #pragma unroll
    for (int i = 0; i < 32; i += 8)
        t[ty + i][tx] = 2.0f * e[(size_t)(k0 + ty + i) * D_DIM + d0 + tx];
    __syncthreads();
    #pragma unroll
    for (int i = 0; i < 32; i += 8)
        eT[(size_t)(d0 + ty + i) * K_DIM + k0 + tx] = t[tx][ty + i];
}

// ---- main: block = 128n x 128k C-tile; 256 threads, split-half 8n x 8k
// micro-tile. LDS double-buffered: zs[2][16][128] + es[2][16][128] = 32 KB.
// All LDS b128 accesses bank-disjoint per 8-lane group (0 conflicts).

__launch_bounds__(256, 4)
__global__ void vq_gemm(const float* __restrict__ z, const float* __restrict__ eT,
                        const float* __restrict__ A, const float* __restrict__ ee,
                        unsigned long long* __restrict__ packed) {
#pragma clang fp contract(off)
    __shared__ __align__(16) float sm[8192];  // [buf][z/e][16][128]; 32 KB

    const int t     = threadIdx.x;
    const int ntile = blockIdx.x & 511;       // low bits: z L3-resident sweep
    const int ktile = blockIdx.x >> 9;
    const int ng0   = ntile * BN;
    const int k0    = ktile * BK;
    const int b     = ng0 >> 12;              // n-tile never spans a batch
    const int hw0   = ng0 & (HW - 1);
    const float* __restrict__ zg = z + (size_t)b * D_DIM * HW + hw0;

    const int lx = t & 15;                    // n-group (stage col & compute)
    const int ky = t >> 4;                    // k-group (compute) == stage row
    const int sd = t >> 4;                    // staging d-row 0..15

    const float* __restrict__ zsrc = zg + (size_t)sd * HW;
    const float* __restrict__ esrc = eT + (size_t)sd * K_DIM + k0;

    // prologue: load chunk 0, stage to buf0, issue chunk 1
    float4 la0 = *(const float4*)(zsrc + lx * 4);
    float4 la1 = *(const float4*)(zsrc + 64 + lx * 4);
    float4 lb0 = *(const float4*)(esrc + lx * 4);
    float4 lb1 = *(const float4*)(esrc + 64 + lx * 4);
    {
        float* zs0 = sm;
        float* es0 = sm + 4096;
        *(float4*)(zs0 + sd * 128 + lx * 4)      = la0;
        *(float4*)(zs0 + sd * 128 + 64 + lx * 4) = la1;
        *(float4*)(es0 + sd * 128 + lx * 4)      = lb0;
        *(float4*)(es0 + sd * 128 + 64 + lx * 4) = lb1;
        const float* zn = zsrc + (size_t)16 * HW;
        const float* en = esrc + (size_t)16 * K_DIM;
        la0 = *(const float4*)(zn + lx * 4);
        la1 = *(const float4*)(zn + 64 + lx * 4);
        lb0 = *(const float4*)(en + lx * 4);
        lb1 = *(const float4*)(en + 64 + lx * 4);
    }
    __syncthreads();

    float acc[8][8];
    #pragma unroll
    for (int i = 0; i < 8; ++i)
        #pragma unroll
        for (int j = 0; j < 8; ++j) acc[i][j] = 0.0f;

    #pragma unroll 1
    for (int c = 0; c < NCH; ++c) {
        float* zs  = sm + (c & 1) * 2048;
        float* es  = sm + 4096 + (c & 1) * 2048;
        float* zsn = sm + ((c + 1) & 1) * 2048;
        float* esn = sm + 4096 + ((c + 1) & 1) * 2048;
        // stage chunk c+1 into the other buffer (regs hold it; vmcnt wait
        // was covered by chunk c's compute in the previous iteration)
        if (c + 1 < NCH) {
            *(float4*)(zsn + sd * 128 + lx * 4)      = la0;
            *(float4*)(zsn + sd * 128 + 64 + lx * 4) = la1;
            *(float4*)(esn + sd * 128 + lx * 4)      = lb0;
            *(float4*)(esn + sd * 128 + 64 + lx * 4) = lb1;
        }
        // issue chunk c+2's global loads: consumed 1 full chunk later
        if (c + 2 < NCH) {
            const float* zn = zsrc + (size_t)(c + 2) * 16 * HW;
            const float* en = esrc + (size_t)(c + 2) * 16 * K_DIM;
            la0 = *(const float4*)(zn + lx * 4);
            la1 = *(const float4*)(zn + 64 + lx * 4);
            lb0 = *(const float4*)(en + lx * 4);
            lb1 = *(const float4*)(en + 64 + lx * 4);
        }
        // compute chunk c: d = c*16 + dd ascending -> exact per-(n,k) chain
        #pragma unroll
        for (int dd = 0; dd < 16; ++dd) {
            float4 z0 = *(const float4*)(zs + dd * 128 + lx * 4);
            float4 z1 = *(const float4*)(zs + dd * 128 + 64 + lx * 4);
            float4 e0 = *(const float4*)(es + dd * 128 + ky * 4);
            float4 e1 = *(const float4*)(es + dd * 128 + 64 + ky * 4);
            const float zr[8] = {z0.x, z0.y, z0.z, z0.w, z1.x, z1.y, z1.z, z1.w};
            const float er[8] = {e0.x, e0.y, e0.z, e0.w, e1.x, e1.y, e1.z, e1.w};
            #pragma unroll
            for (int i = 0; i < 8; ++i)
                #pragma unroll
                for (int j = 0; j < 8; ++j)
                    acc[i][j] = fmaf(zr[i], er[j], acc[i][j]);
        }
        __syncthreads();   // writes of c+1 visible; buf[c&1] free for c+2
    }

    // ---- epilogue: dist = (An - M2) + ee; per-n best over this block's
    // 128 k's. Within thread: j ascending == k ascending (ky*4+3 < 64+ky*4).
    // LDS reduce over 16 ky-groups, then one device atomicMin per n.
    unsigned long long* red = (unsigned long long*)sm;  // [128][16], 16 KB
    #pragma unroll
    for (int i = 0; i < 8; ++i) {
        const int n_l = (i < 4) ? (lx * 4 + i) : (64 + lx * 4 + i - 4);
        const float An = A[ng0 + n_l];
        float bv = F32MAX;
        int   bk = 0;
        #pragma unroll
        for (int j = 0; j < 8; ++j) {
            const int k_l = (j < 4) ? (ky * 4 + j) : (64 + ky * 4 + j - 4);
            const int k = k0 + k_l;
            const float dist = (An - acc[i][j]) + ee[k];
            if (dist < bv) { bv = dist; bk = k; }
        }
        unsigned int vb = __float_as_uint(bv);
        vb = (vb & 0x80000000u) ? ~vb : (vb | 0x80000000u);
        red[n_l * 16 + ky] = ((unsigned long long)vb << 32) | (unsigned int)bk;
    }
    __syncthreads();
    if (t < BN) {
        unsigned long long m = red[t * 16];
        #pragma unroll
        for (int q = 1; q < 16; ++q) {
            const unsigned long long v = red[t * 16 + q];
            if (v < m) m = v;
        }
        atomicMin(&packed[ng0 + t], m);
    }
}

__global__ void unpack_kernel(const unsigned long long* __restrict__ packed,
                              int* __restrict__ out) {
    int n = blockIdx.x * blockDim.x + threadIdx.x;
    out[n] = (int)(packed[n] & 0xFFFFFFFFull);
}

extern "C" void kernel_launch(void* const* d_in, const int* in_sizes, int n_in,
                              void* d_out, int out_size, void* d_ws, size_t ws_size,
                              hipStream_t stream) {
    const float* z   = (const float*)d_in[0];   // [16,256,64,64]
    const float* emb = (const float*)d_in[1];   // [1024,256]
    int* out = (int*)d_out;                     // [65536] int32

    float* wsEE = (float*)d_ws;                     // 1024
    float* wsA  = wsEE + K_DIM;                     // 65536
    float* wsET = wsA + N_TOT;                      // 262144
    unsigned long long* wsPacked =
        (unsigned long long*)(wsET + (size_t)D_DIM * K_DIM);  // 65536 u64

    hipMemsetAsync(wsPacked, 0xFF, (size_t)N_TOT * sizeof(unsigned long long),
                   stream);
    et_kernel<<<dim3(K_DIM / 32, D_DIM / 32), dim3(32, 8), 0, stream>>>(emb, wsET);
    ee_kernel<<<K_DIM / 256, 256, 0, stream>>>(emb, wsEE);
    a_kernel<<<2 * N_TOT / 256, 256, 0, stream>>>(z, wsA);
    vq_gemm<<<(N_TOT / BN) * (K_DIM / BK), 256, 0, stream>>>(z, wsET, wsA, wsEE,
                                                             wsPacked);
    unpack_kernel<<<N_TOT / 256, 256, 0, stream>>>(wsPacked, out);
}

// Round 8
// 502.716 us; speedup vs baseline: 2.6214x; 2.6214x over previous
//
#include <hip/hip_runtime.h>

// VQ argmin: exact bit-level emulation of numpy fp32 reference:
//   A  = np.sum(flat*flat, axis=1)     (numpy pairwise-sum tree, fp32)
//   M2 = (2*flat) @ emb.T              (BLAS: sequential fp32 fma chain over d)
//   dist = (A - M2) + ee;  argmin_k (first-min ties)
// z_e_x: [B=16, D=256, H=64, W=64] fp32; embedding: [K=1024, D=256] fp32
// out: int32 [65536]
//
// R11: consolidation of the measured optimum across R0-R10.
//   vq: R3's exact body (KT=64, NKT=4, NSPLIT=4, launch_bounds(256,4),
//       grid 1024 = 4 blocks/CU, z VGPR ping-pong, eT via SGPR broadcast,
//       no LDS) -- the only structure that reached 409us. LDS-GEMM (R9/R10:
//       1020/1243), occupancy pushes (R4/R5: spill), A-fusion (R6/R7:
//       472/558), 2n/KT=32 (R8: 505) all measured worse. R3's 31% stall is
//       pinned by the SGPR file (112): one 64-float er row resident ->
//       s_load latency only partially hidden; no tiling changes that.
//   aux: R8's proven stack -- split a_kernel (2 threads/n, ~20us), LDS-tiled
//       et (~10us), u64 (distbits,k) atomicMin combine + unpack (verified
//       absmax=0 in R4/R5/R8/R9/R10).

#define D_DIM  256
#define K_DIM  1024
#define HW     4096
#define N_TOT  65536
#define NSPLIT 4
#define NKT    4
#define KT     64                 // acc regs per thread
#define KSPL   (K_DIM / NSPLIT)   // 256 k's per split = NKT*KT
#define F32MAX 3.402823466e38f

// ---- numpy pairwise_sum for ||e_k||^2 (n=256 = two 128-blocks of 8 accs)

__global__ void ee_kernel(const float* __restrict__ e, float* __restrict__ ee) {
#pragma clang fp contract(off)
    int k = blockIdx.x * blockDim.x + threadIdx.x;
    if (k >= K_DIM) return;
    const float* row = e + (size_t)k * D_DIM;
    float total = 0.0f;
    #pragma unroll
    for (int h = 0; h < 2; ++h) {
        const float* a = row + h * 128;
        float r[8];
        #pragma unroll
        for (int j = 0; j < 8; ++j) { float v = a[j]; r[j] = v * v; }
        #pragma unroll
        for (int i = 8; i < 128; i += 8) {
            #pragma unroll
            for (int j = 0; j < 8; ++j) { float v = a[i + j]; r[j] = r[j] + v * v; }
        }
        float s = ((r[0] + r[1]) + (r[2] + r[3])) + ((r[4] + r[5]) + (r[6] + r[7]));
        total = (h == 0) ? s : (total + s);
    }
    ee[k] = total;
}

// ---- A = numpy pairwise ||z_n||^2: 2 threads per n, one 128-half each
// (halves are independent 8-acc chains; total = s0 + s1). Bitwise-exact.

__global__ void a_kernel(const float* __restrict__ z, float* __restrict__ A) {
#pragma clang fp contract(off)
    int t = blockIdx.x * blockDim.x + threadIdx.x;   // 0 .. 2*N_TOT-1
    int n = t >> 1;
    int h = t & 1;
    int b  = n >> 12;
    int hw = n & (HW - 1);
    const float* base = z + (size_t)b * D_DIM * HW + hw + (size_t)(h * 128) * HW;
    float r[8];
    #pragma unroll
    for (int j = 0; j < 8; ++j) { float v = base[(size_t)j * HW]; r[j] = v * v; }
    #pragma unroll
    for (int i = 8; i < 128; i += 8) {
        #pragma unroll
        for (int j = 0; j < 8; ++j) {
            float v = base[(size_t)(i + j) * HW];
            r[j] = r[j] + v * v;
        }
    }
    float s = ((r[0] + r[1]) + (r[2] + r[3])) + ((r[4] + r[5]) + (r[6] + r[7]));
    float other = __shfl_xor(s, 1);
    if (h == 0) A[n] = s + other;    // total = s_half0 + s_half1 (exact order)
}

// ---- transpose + fold the exact x2: eT[d][k] = 2*emb[k][d]

__global__ void et_kernel(const float* __restrict__ e, float* __restrict__ eT) {
    __shared__ float t[32][33];
    const int k0 = blockIdx.x * 32;
    const int d0 = blockIdx.y * 32;
    const int tx = threadIdx.x;         // 0..31
    const int ty = threadIdx.y;         // 0..7
    #pragma unroll
    for (int i = 0; i < 32; i += 8)
        t[ty + i][tx] = 2.0f * e[(size_t)(k0 + ty + i) * D_DIM + d0 + tx];
    __syncthreads();
    #pragma unroll
    for (int i = 0; i < 32; i += 8)
        eT[(size_t)(d0 + ty + i) * K_DIM + k0 + tx] = t[tx][ty + i];
}

// ---- one full-D pass over a KT-wide k tile (R3's exact uniform body):
// z VGPR ping-pong prefetch, eT rows wave-uniform -> SGPR broadcast operand.

__device__ __forceinline__ void kt_pass(const float* __restrict__ zp,
                                        const float* __restrict__ eT,
                                        int kbase,
                                        float (&za)[8], float (&zb)[8],
                                        float (&acc)[KT]) {
#pragma clang fp contract(off)
    #pragma unroll 1
    for (int it = 0; it < 16; ++it) {
        const int base = it * 16;
        // prefetch d = base+8 .. base+15
        #pragma unroll
        for (int i = 0; i < 8; ++i)
            zb[i] = zp[(size_t)((base + 8 + i) & (D_DIM - 1)) * HW];
        // compute d = base .. base+7 (ascending: exact fma chain)
        #pragma unroll
        for (int dd = 0; dd < 8; ++dd) {
            const float zv = za[dd];
            const float* __restrict__ er = eT + (size_t)(base + dd) * K_DIM + kbase;
            #pragma unroll
            for (int j = 0; j < KT; ++j)
                acc[j] = fmaf(zv, er[j], acc[j]);   // er[j] -> SGPR operand
        }
        // prefetch d = base+16 .. base+23; (mod 256) wrap at it=15 re-primes
        // za with d=0..7 for the next kt pass automatically.
        #pragma unroll
        for (int i = 0; i < 8; ++i)
            za[i] = zp[(size_t)((base + 16 + i) & (D_DIM - 1)) * HW];
        // compute d = base+8 .. base+15
        #pragma unroll
        for (int dd = 0; dd < 8; ++dd) {
            const float zv = zb[dd];
            const float* __restrict__ er = eT + (size_t)(base + 8 + dd) * K_DIM + kbase;
            #pragma unroll
            for (int j = 0; j < KT; ++j)
                acc[j] = fmaf(zv, er[j], acc[j]);
        }
    }
}

// ---- main: 1 n per thread, eT broadcast via SGPRs, 64-k acc tile, no LDS.
// R3-proven operating point: 4 blocks/CU, 4 waves/SIMD, 128-reg budget.
// Block-id layout: s = id & 3 -> each XCD (id mod 8) hosts a single s
// value, so its L2 holds one 256 KB eT slice (accidental but load-bearing).

__launch_bounds__(256, 4)
__global__ void vq_partial(const float* __restrict__ z, const float* __restrict__ eT,
                           const float* __restrict__ A, const float* __restrict__ ee,
                           unsigned long long* __restrict__ packed) {
#pragma clang fp contract(off)
    const int tid  = threadIdx.x;
    const int s    = blockIdx.x & (NSPLIT - 1);
    const int slab = blockIdx.x >> 2;
    const int n    = slab * 256 + tid;
    const int b    = n >> 12;
    const int hw   = n & (HW - 1);
    const float* __restrict__ zp = z + (size_t)b * D_DIM * HW + hw;
    const int kb0 = s * KSPL;

    const float An = A[n];
    float bestv = F32MAX;
    int   bestk = 0;
    float za[8], zb[8];

    // prime za with d = 0..7
    #pragma unroll
    for (int i = 0; i < 8; ++i) za[i] = zp[(size_t)i * HW];

    #pragma unroll 1
    for (int kt = 0; kt < NKT; ++kt) {
        const int kbase = kb0 + kt * KT;
        float acc[KT];
        #pragma unroll
        for (int j = 0; j < KT; ++j) acc[j] = 0.0f;
        kt_pass(zp, eT, kbase, za, zb, acc);
        // epilogue: dist = (An - M2) + ee, k ascending -> first-min ties
        #pragma unroll
        for (int j = 0; j < KT; ++j) {
            const float dist = (An - acc[j]) + ee[kbase + j];
            if (dist < bestv) { bestv = dist; bestk = kbase + j; }
        }
    }

    // Order-preserving fp32 encode; lexicographic (dist, k) min across
    // splits. Equal dist bits -> lower k wins = first-min semantics.
    unsigned int vb = __float_as_uint(bestv);
    vb = (vb & 0x80000000u) ? ~vb : (vb | 0x80000000u);
    atomicMin(&packed[n], ((unsigned long long)vb << 32) | (unsigned int)bestk);
}

__global__ void unpack_kernel(const unsigned long long* __restrict__ packed,
                              int* __restrict__ out) {
    int n = blockIdx.x * blockDim.x + threadIdx.x;
    out[n] = (int)(packed[n] & 0xFFFFFFFFull);
}

extern "C" void kernel_launch(void* const* d_in, const int* in_sizes, int n_in,
                              void* d_out, int out_size, void* d_ws, size_t ws_size,
                              hipStream_t stream) {
    const float* z   = (const float*)d_in[0];   // [16,256,64,64]
    const float* emb = (const float*)d_in[1];   // [1024,256]
    int* out = (int*)d_out;                     // [65536] int32

    float* wsEE = (float*)d_ws;                     // 1024
    float* wsA  = wsEE + K_DIM;                     // 65536
    float* wsET = wsA + N_TOT;                      // 262144
    unsigned long long* wsPacked =
        (unsigned long long*)(wsET + (size_t)D_DIM * K_DIM);  // 65536 u64

    hipMemsetAsync(wsPacked, 0xFF, (size_t)N_TOT * sizeof(unsigned long long),
                   stream);
    et_kernel<<<dim3(K_DIM / 32, D_DIM / 32), dim3(32, 8), 0, stream>>>(emb, wsET);
    ee_kernel<<<K_DIM / 256, 256, 0, stream>>>(emb, wsEE);
    a_kernel<<<2 * N_TOT / 256, 256, 0, stream>>>(z, wsA);
    vq_partial<<<N_TOT / 256 * NSPLIT, 256, 0, stream>>>(z, wsET, wsA, wsEE,
                                                         wsPacked);
    unpack_kernel<<<N_TOT / 256, 256, 0, stream>>>(wsPacked, out);
}